// Round 10
// baseline (776.627 us; speedup 1.0000x reference)
//
#include <hip/hip_runtime.h>
#include <hip/hip_fp16.h>

#define HEADS 4
#define DH    32
#define HW    4096
#define CIN   256
#define HID   128

using half8   = __attribute__((ext_vector_type(8))) _Float16;
using half4   = __attribute__((ext_vector_type(4))) _Float16;
using half2v  = __attribute__((ext_vector_type(2))) _Float16;
using floatx4 = __attribute__((ext_vector_type(4))) float;

// P = exp2(s_log2 - 3*log2e); log2(e) folded into Q pre-scale, shift folded
// into the S-MFMA C-initializer.
#define SHIFT2 4.328085122666891f
#define WQSCALE 0.25508275947f   // 32^-0.5 * log2(e)

// packed f32x2 -> f16x2 (cvt_pkrtz returns __fp16 vec; bit-cast to _Float16 vec)
static __device__ __forceinline__ half2v pk2(float a, float b) {
  return __builtin_bit_cast(half2v, __builtin_amdgcn_cvt_pkrtz(a, b));
}

// ---------------------------------------------------------------------------
// qkv_fused: QKV[o][b,p] = (w_qkv f32->f16, Q rows pre-scaled) @ x^T.
// x transposed through fp32 t[64][65] LDS tile, K in 4 quarters of 64.
// grid (6 m-tiles, 256 n-tiles) x 256
// ---------------------------------------------------------------------------
__global__ __launch_bounds__(256) void qkv_fused(
    const float* __restrict__ w, const float* __restrict__ x,
    _Float16* __restrict__ Qw, _Float16* __restrict__ Kw,
    _Float16* __restrict__ Vtw)
{
  __shared__ float t[64][65];
  __shared__ _Float16 As[64][72];
  __shared__ _Float16 Bs[64][72];
  const int mt = blockIdx.x, nt = blockIdx.y;
  const int b = nt >> 6, p0 = (nt & 63) * 64;
  const int tid = threadIdx.x;
  const int wv = tid >> 6, lane = tid & 63, lm = lane & 15, quad = lane >> 4;
  const float wscale = (mt < 2) ? WQSCALE : 1.0f;

  const float* Ag = w + (size_t)(mt * 64) * CIN;
  const float* xb = x + (size_t)b * CIN * HW + p0;

  floatx4 acc[4] = {{0,0,0,0},{0,0,0,0},{0,0,0,0},{0,0,0,0}};

  for (int kq = 0; kq < 4; ++kq) {
    __syncthreads();
    #pragma unroll
    for (int i = 0; i < 4; ++i) {
      int ci = tid + i * 256;
      int cc = ci >> 4, p4 = (ci & 15) * 4;
      *(float4*)&t[cc][p4] =
          *(const float4*)(xb + (size_t)(kq * 64 + cc) * HW + p4);
    }
    #pragma unroll
    for (int i = 0; i < 2; ++i) {
      int ci = tid + i * 256;
      int r = ci >> 3, c8 = (ci & 7) * 8;
      const float* src = Ag + (size_t)r * CIN + kq * 64 + c8;
      float4 u0 = *(const float4*)(src);
      float4 u1 = *(const float4*)(src + 4);
      half8 h = {(_Float16)(u0.x * wscale), (_Float16)(u0.y * wscale),
                 (_Float16)(u0.z * wscale), (_Float16)(u0.w * wscale),
                 (_Float16)(u1.x * wscale), (_Float16)(u1.y * wscale),
                 (_Float16)(u1.z * wscale), (_Float16)(u1.w * wscale)};
      *(half8*)&As[r][c8] = h;
    }
    __syncthreads();
    #pragma unroll
    for (int i = 0; i < 2; ++i) {
      int idx = tid + i * 256;
      int p = idx >> 3, c0 = (idx & 7) * 8;
      half8 v;
      #pragma unroll
      for (int k = 0; k < 8; ++k) v[k] = (_Float16)t[c0 + k][p];
      *(half8*)&Bs[p][c0] = v;
    }
    __syncthreads();
    #pragma unroll
    for (int ks = 0; ks < 2; ++ks) {
      half8 a = *(const half8*)&As[wv * 16 + lm][ks * 32 + quad * 8];
      #pragma unroll
      for (int ns = 0; ns < 4; ++ns) {
        half8 bf = *(const half8*)&Bs[ns * 16 + lm][ks * 32 + quad * 8];
        acc[ns] = __builtin_amdgcn_mfma_f32_16x16x32_f16(a, bf, acc[ns], 0, 0, 0);
      }
    }
  }

  const int sec = mt >> 1;                    // 0=Q 1=K 2=V
  const int o_base = (mt & 1) * 64 + wv * 16 + quad * 4;
  const int hh = o_base >> 5, dd = o_base & 31;
  const int bh = b * HEADS + hh;
  if (sec < 2) {
    _Float16* dst = (sec == 0) ? Qw : Kw;
    #pragma unroll
    for (int ns = 0; ns < 4; ++ns) {
      int p = p0 + ns * 16 + lm;
      half4 v = {(_Float16)acc[ns][0], (_Float16)acc[ns][1],
                 (_Float16)acc[ns][2], (_Float16)acc[ns][3]};
      *(half4*)(dst + ((size_t)bh * HW + p) * DH + dd) = v;
    }
  } else {
    #pragma unroll
    for (int ns = 0; ns < 4; ++ns) {
      int p = p0 + ns * 16 + lm;
      #pragma unroll
      for (int r = 0; r < 4; ++r)
        Vtw[((size_t)bh * DH + dd + r) * HW + p] = (_Float16)acc[ns][r];
    }
  }
}

// ---------------------------------------------------------------------------
// attn: software-pipelined register-dataflow flash attention.
// Phase-batched per 128-kcol iteration to de-interleave the pipes:
//   S-phase(it): 16 MFMAs  ->  PV-phase(it-1): 48 MFMAs (pbP from last iter,
//   V-tile still live in the other ping-pong buffer)  ->  exp-phase(it): pure
//   VALU, no dependent MFMA until next iteration.
// A wave's VALU burst overlaps queued MFMA bursts (own + sibling waves').
// Buffer schedule (verified): S(it) reads ks[it&1] (staged at it-1);
// PV(it) reads vt[(it&1)^1] (staged at it-2 = tiles of it-1); staging at it
// writes tiles(it+1) into nx after barrier A. vt[1] pre-filled for it=0.
// Prefetch double-sets: issued at iteration top, drained (vmcnt0) only at
// barrier A ~full-iteration later. grid (32 q-tiles, 16 bh) x 256.
// ---------------------------------------------------------------------------
__global__ __launch_bounds__(256) void attn(
    const _Float16* __restrict__ Qw, const _Float16* __restrict__ Kw,
    const _Float16* __restrict__ Vtw, _Float16* __restrict__ Ot)
{
  __shared__ _Float16 ks[2][2][64][40];       // [phase][sub][kcol][d]  20.0 KB
  __shared__ _Float16 vt[2][2][32][76];       // [phase][sub][d][kcol]  19.0 KB

  const int bh = blockIdx.y, qt = blockIdx.x;
  const int tid = threadIdx.x;
  const int wv = tid >> 6, lane = tid & 63, lm = lane & 15, quad = lane >> 4;

  const _Float16* qbase =
      Qw + ((size_t)bh * HW + qt * 128 + wv * 16 + lm) * DH + quad * 8;
  const half8 qa0 = *(const half8*)qbase;
  const half8 qa1 = *(const half8*)(qbase + (size_t)64 * DH);

  const _Float16 one = (_Float16)1.0f;
  const half4 ones4 = {one, one, one, one};
  const floatx4 shiftc = {-SHIFT2, -SHIFT2, -SHIFT2, -SHIFT2};

  floatx4 oT[2][2] = {{{0,0,0,0},{0,0,0,0}},{{0,0,0,0},{0,0,0,0}}};
  floatx4 l4[2]    = {{0,0,0,0},{0,0,0,0}};
  half4 pbP[8][2];                            // P(it-1) fragments
  #pragma unroll
  for (int ff = 0; ff < 8; ++ff) {
    pbP[ff][0] = half4{0,0,0,0};
    pbP[ff][1] = half4{0,0,0,0};
  }

  const _Float16* kbase = Kw  + (size_t)bh * HW * DH;
  const _Float16* vbase = Vtw + (size_t)bh * DH * HW;
  const int kr = tid >> 2, kc = (tid & 3) * 8;
  const int vr = tid >> 3, vc = (tid & 7) * 8;

  // prologue: stage tile-pair 0 (subtiles 0,1) into buf0; NaN-guard vt[1];
  // prefetch set0 = tile-pair 1 (subtiles 2,3).
  {
    half8 k0 = *(const half8*)(kbase + (size_t)kr * DH + kc);
    half8 v0 = *(const half8*)(vbase + (size_t)vr * HW + vc);
    half8 k1 = *(const half8*)(kbase + ((size_t)64 + kr) * DH + kc);
    half8 v1 = *(const half8*)(vbase + (size_t)vr * HW + 64 + vc);
    *(half8*)&ks[0][0][kr][kc] = k0;
    *(half8*)&vt[0][0][vr][vc] = v0;
    *(half8*)&ks[0][1][kr][kc] = k1;
    *(half8*)&vt[0][1][vr][vc] = v1;
    *(half8*)&vt[1][0][vr][vc] = v0;          // guard: it=0 PV reads vt[1] x 0
    *(half8*)&vt[1][1][vr][vc] = v1;
  }
  half8 kS[2][2], vS[2][2];                   // prefetch sets [set][sub]
  kS[0][0] = *(const half8*)(kbase + ((size_t)128 + kr) * DH + kc);
  vS[0][0] = *(const half8*)(vbase + (size_t)vr * HW + 128 + vc);
  kS[0][1] = *(const half8*)(kbase + ((size_t)192 + kr) * DH + kc);
  vS[0][1] = *(const half8*)(vbase + (size_t)vr * HW + 192 + vc);
  __syncthreads();

  for (int it = 0; it < HW / 128; ++it) {
    const int ph = it & 1, nx = ph ^ 1;
    const int cs = it & 1;                    // consume set (staged below)
    const int pf = cs ^ 1;                    // prefetch target set
    // top: prefetch tile-pair (it+2) — drained only at barrier A (long window)
    size_t koff = (size_t)(it * 2 + 4) * 64;
    if (koff > HW - 128) koff = HW - 128;
    kS[pf][0] = *(const half8*)(kbase + (koff + kr) * DH + kc);
    vS[pf][0] = *(const half8*)(vbase + (size_t)vr * HW + koff + vc);
    kS[pf][1] = *(const half8*)(kbase + (koff + 64 + kr) * DH + kc);
    vS[pf][1] = *(const half8*)(vbase + (size_t)vr * HW + koff + 64 + vc);

    // --- S-phase(it): 16 independent MFMAs ---
    floatx4 sT[8][2];
    #pragma unroll
    for (int ff = 0; ff < 8; ++ff) {
      half8 kb = *(const half8*)&ks[ph][ff >> 2][(ff & 3) * 16 + lm][quad * 8];
      sT[ff][0] = __builtin_amdgcn_mfma_f32_16x16x32_f16(kb, qa0, shiftc, 0, 0, 0);
      sT[ff][1] = __builtin_amdgcn_mfma_f32_16x16x32_f16(kb, qa1, shiftc, 0, 0, 0);
    }
    // --- PV-phase(it-1): 48 MFMAs off pbP, V-tile in vt[nx] ---
    #pragma unroll
    for (int ff = 0; ff < 8; ++ff) {
      l4[0] = __builtin_amdgcn_mfma_f32_16x16x16f16(ones4, pbP[ff][0], l4[0], 0, 0, 0);
      l4[1] = __builtin_amdgcn_mfma_f32_16x16x16f16(ones4, pbP[ff][1], l4[1], 0, 0, 0);
      #pragma unroll
      for (int g = 0; g < 2; ++g) {
        half4 va = *(const half4*)&vt[nx][ff >> 2][g * 16 + lm][(ff & 3) * 16 + quad * 4];
        oT[0][g] = __builtin_amdgcn_mfma_f32_16x16x16f16(va, pbP[ff][0], oT[0][g], 0, 0, 0);
        oT[1][g] = __builtin_amdgcn_mfma_f32_16x16x16f16(va, pbP[ff][1], oT[1][g], 0, 0, 0);
      }
    }
    // --- exp-phase(it): pure VALU, overlaps MFMA pipe drain ---
    #pragma unroll
    for (int ff = 0; ff < 8; ++ff) {
      #pragma unroll
      for (int t = 0; t < 2; ++t) {
        half2v lo = pk2(__builtin_amdgcn_exp2f(sT[ff][t][0]),
                        __builtin_amdgcn_exp2f(sT[ff][t][1]));
        half2v hi = pk2(__builtin_amdgcn_exp2f(sT[ff][t][2]),
                        __builtin_amdgcn_exp2f(sT[ff][t][3]));
        pbP[ff][t] = half4{lo.x, lo.y, hi.x, hi.y};
      }
    }
    __syncthreads();                          // A: vt[nx] reads done; vmcnt drain
    // staging: tile-pair (it+1) from set[cs] -> buffers nx
    *(half8*)&ks[nx][0][kr][kc] = kS[cs][0];
    *(half8*)&vt[nx][0][vr][vc] = vS[cs][0];
    *(half8*)&ks[nx][1][kr][kc] = kS[cs][1];
    *(half8*)&vt[nx][1][vr][vc] = vS[cs][1];
    __syncthreads();                          // B: nx ready for it+1's S
  }

  // drain: PV for P(last). Last it=31: its V tile-pair 31 lives in vt[1]
  // (staged at it=30, untouched since).
  #pragma unroll
  for (int ff = 0; ff < 8; ++ff) {
    l4[0] = __builtin_amdgcn_mfma_f32_16x16x16f16(ones4, pbP[ff][0], l4[0], 0, 0, 0);
    l4[1] = __builtin_amdgcn_mfma_f32_16x16x16f16(ones4, pbP[ff][1], l4[1], 0, 0, 0);
    #pragma unroll
    for (int g = 0; g < 2; ++g) {
      half4 va = *(const half4*)&vt[1][ff >> 2][g * 16 + lm][(ff & 3) * 16 + quad * 4];
      oT[0][g] = __builtin_amdgcn_mfma_f32_16x16x16f16(va, pbP[ff][0], oT[0][g], 0, 0, 0);
      oT[1][g] = __builtin_amdgcn_mfma_f32_16x16x16f16(va, pbP[ff][1], oT[1][g], 0, 0, 0);
    }
  }

  // epilogue: lane-local normalize, coalesced half4 stores -> Ot[b][p][hid]
  const int b = bh >> 2, hh = bh & 3;
  #pragma unroll
  for (int t = 0; t < 2; ++t) {
    const float inv = 1.0f / l4[t][0];
    _Float16* obase = Ot +
        ((size_t)(b * HW + qt * 128 + t * 64 + wv * 16 + lm)) * HID + hh * DH;
    #pragma unroll
    for (int g = 0; g < 2; ++g) {
      half4 v = {(_Float16)(oT[t][g][0] * inv), (_Float16)(oT[t][g][1] * inv),
                 (_Float16)(oT[t][g][2] * inv), (_Float16)(oT[t][g][3] * inv)};
      *(half4*)(obase + g * 16 + quad * 4) = v;
    }
  }
}

// ---------------------------------------------------------------------------
// out_gemm: out[o][b,p] = w_out(256x128, cvt inline) @ Ot^T + bias.
// Tile 64x64, K=128. grid (4 m-tiles, 256 n-tiles) x 256.
// ---------------------------------------------------------------------------
__global__ __launch_bounds__(256) void out_gemm(
    const float* __restrict__ wo, const _Float16* __restrict__ Ot,
    const float* __restrict__ bo, float* __restrict__ out)
{
  __shared__ _Float16 As[64][136];
  __shared__ _Float16 Bs[64][136];
  __shared__ float os[64][68];
  const int mt = blockIdx.x, nt = blockIdx.y;
  const int b = nt >> 6, p0 = (nt & 63) * 64;
  const int tid = threadIdx.x;
  const int wv = tid >> 6, lane = tid & 63, lm = lane & 15, quad = lane >> 4;

  const float* Ag = wo + (size_t)(mt * 64) * HID;
  const _Float16* B = Ot + ((size_t)b * HW + p0) * HID;

  #pragma unroll
  for (int i = 0; i < 4; ++i) {
    int ci = tid + i * 256;
    int r = ci >> 4, c8 = (ci & 15) * 8;
    const float* src = Ag + (size_t)r * HID + c8;
    float4 u0 = *(const float4*)(src);
    float4 u1 = *(const float4*)(src + 4);
    half8 h = {(_Float16)u0.x, (_Float16)u0.y, (_Float16)u0.z, (_Float16)u0.w,
               (_Float16)u1.x, (_Float16)u1.y, (_Float16)u1.z, (_Float16)u1.w};
    *(half8*)&As[r][c8] = h;
    *(half8*)&Bs[r][c8] = *(const half8*)(B + (size_t)r * HID + c8);
  }
  __syncthreads();

  floatx4 acc[4] = {{0,0,0,0},{0,0,0,0},{0,0,0,0},{0,0,0,0}};
  #pragma unroll
  for (int ks = 0; ks < 4; ++ks) {
    half8 a = *(const half8*)&As[wv * 16 + lm][ks * 32 + quad * 8];
    #pragma unroll
    for (int ns = 0; ns < 4; ++ns) {
      half8 bf = *(const half8*)&Bs[ns * 16 + lm][ks * 32 + quad * 8];
      acc[ns] = __builtin_amdgcn_mfma_f32_16x16x32_f16(a, bf, acc[ns], 0, 0, 0);
    }
  }

  #pragma unroll
  for (int ns = 0; ns < 4; ++ns)
    #pragma unroll
    for (int r = 0; r < 4; ++r)
      os[wv * 16 + quad * 4 + r][ns * 16 + lm] = acc[ns][r];
  __syncthreads();

  const int o = tid >> 2, pq = (tid & 3) * 16;
  const float bias = bo[mt * 64 + o];
  float* dst = out + ((size_t)(b * CIN + mt * 64 + o)) * HW + p0 + pq;
  #pragma unroll
  for (int j = 0; j < 4; ++j) {
    float4 v = *(const float4*)&os[o][pq + j * 4];
    v.x += bias; v.y += bias; v.z += bias; v.w += bias;
    *(float4*)(dst + j * 4) = v;
  }
}

// ---------------------------------------------------------------------------
extern "C" void kernel_launch(void* const* d_in, const int* in_sizes, int n_in,
                              void* d_out, int out_size, void* d_ws, size_t ws_size,
                              hipStream_t stream)
{
  const float* x     = (const float*)d_in[0];   // [4,256,64,64]
  const float* w_qkv = (const float*)d_in[1];   // [384,256]
  const float* w_out = (const float*)d_in[2];   // [256,128]
  const float* b_out = (const float*)d_in[3];   // [256]
  float* out = (float*)d_out;

  char* ws = (char*)d_ws;
  _Float16* Ot  = (_Float16*)(ws);               // 4 MB [4][4096][128]
  _Float16* Qw  = (_Float16*)(ws + (8u  << 20)); // 4 MB [bh][p][d], log2e-scaled
  _Float16* Kw  = (_Float16*)(ws + (12u << 20)); // 4 MB [bh][p][d]
  _Float16* Vtw = (_Float16*)(ws + (16u << 20)); // 4 MB [bh][d][p]

  dim3 blk(256);
  qkv_fused<<<dim3(6, 256), blk, 0, stream>>>(w_qkv, x, Qw, Kw, Vtw);
  attn<<<dim3(32, 16), blk, 0, stream>>>(Qw, Kw, Vtw, Ot);
  out_gemm<<<dim3(4, 256), blk, 0, stream>>>(w_out, Ot, b_out, out);
}

// Round 11
// 165.265 us; speedup vs baseline: 4.6993x; 4.6993x over previous
//
#include <hip/hip_runtime.h>
#include <hip/hip_fp16.h>

#define HEADS 4
#define DH    32
#define HW    4096
#define CIN   256
#define HID   128

using half8   = __attribute__((ext_vector_type(8))) _Float16;
using half4   = __attribute__((ext_vector_type(4))) _Float16;
using half2v  = __attribute__((ext_vector_type(2))) _Float16;
using floatx4 = __attribute__((ext_vector_type(4))) float;

// P = exp2(s_log2 - 3*log2e); log2(e) folded into Q pre-scale, shift folded
// into the S-MFMA C-initializer.
#define SHIFT2 4.328085122666891f
#define WQSCALE 0.25508275947f   // 32^-0.5 * log2(e)

// packed f32x2 -> f16x2 (cvt_pkrtz returns __fp16 vec; bit-cast to _Float16 vec)
static __device__ __forceinline__ half2v pk2(float a, float b) {
  return __builtin_bit_cast(half2v, __builtin_amdgcn_cvt_pkrtz(a, b));
}

// ---------------------------------------------------------------------------
// conv_x: x [b][c][p] fp32 -> Xh [b][p][c] f16 (transpose via LDS)
// grid (64 p-tiles, 4 c-tiles, 4 b) x 256. Bandwidth-bound (24 MB traffic).
// ---------------------------------------------------------------------------
__global__ __launch_bounds__(256) void conv_x(
    const float* __restrict__ x, _Float16* __restrict__ Xh)
{
  __shared__ float t[64][65];
  const int b = blockIdx.z, ct = blockIdx.y, pt = blockIdx.x;
  const int tid = threadIdx.x;
  const float* src = x + ((size_t)(b * CIN + ct * 64)) * HW + pt * 64;
  #pragma unroll
  for (int i = 0; i < 16; ++i) {
    int idx = tid + i * 256;
    int c = idx >> 6, p = idx & 63;
    t[c][p] = src[(size_t)c * HW + p];
  }
  __syncthreads();
  #pragma unroll
  for (int pass = 0; pass < 2; ++pass) {
    int p = (tid >> 3) + pass * 32;
    int c0 = (tid & 7) * 8;
    half8 v;
    #pragma unroll
    for (int j = 0; j < 8; ++j) v[j] = (_Float16)t[c0 + j][p];
    *(half8*)(Xh + ((size_t)(b * HW + pt * 64 + p)) * CIN + ct * 64 + c0) = v;
  }
}

// ---------------------------------------------------------------------------
// qkv_gemm: QKV[o][b,p] = (w_qkv cvt inline, Q rows pre-scaled) @ Xh^T.
// Tile 64(o) x 128(p), K=256 in 2 halves with REGISTER PREFETCH of half 1
// during half 0's MFMAs (one exposed global-latency window, 3 barriers).
// Epilogue scatters Qw/Kw [bh][p][d] (8B) and Vtw [bh][d][p].
// grid (6 m-tiles, 128 n-tiles) x 256
// ---------------------------------------------------------------------------
__global__ __launch_bounds__(256) void qkv_gemm(
    const float* __restrict__ w, const _Float16* __restrict__ Xh,
    _Float16* __restrict__ Qw, _Float16* __restrict__ Kw,
    _Float16* __restrict__ Vtw)
{
  __shared__ _Float16 As[64][136];            // 17.4 KB
  __shared__ _Float16 Bs[128][136];           // 34.8 KB -> 52 KB total
  const int mt = blockIdx.x, nt = blockIdx.y;
  const int b = nt >> 5, p0 = (nt & 31) * 128;
  const int tid = threadIdx.x;
  const int wv = tid >> 6, lane = tid & 63, lm = lane & 15, quad = lane >> 4;
  const float wscale = (mt < 2) ? WQSCALE : 1.0f;

  const float* Ag = w + (size_t)(mt * 64) * CIN;
  const _Float16* Bg = Xh + ((size_t)b * HW + p0) * CIN;

  float4 apre[4][2];
  half8  bpre[8];
  // prefetch kh=0
  #pragma unroll
  for (int i = 0; i < 4; ++i) {
    int ci = tid + i * 256, r = ci >> 4, c8 = (ci & 15) * 8;
    const float* s = Ag + (size_t)r * CIN + c8;
    apre[i][0] = *(const float4*)s;
    apre[i][1] = *(const float4*)(s + 4);
  }
  #pragma unroll
  for (int i = 0; i < 8; ++i) {
    int ci = tid + i * 256, r = ci >> 4, c8 = (ci & 15) * 8;
    bpre[i] = *(const half8*)(Bg + (size_t)r * CIN + c8);
  }

  floatx4 acc[8] = {{0,0,0,0},{0,0,0,0},{0,0,0,0},{0,0,0,0},
                    {0,0,0,0},{0,0,0,0},{0,0,0,0},{0,0,0,0}};

  #pragma unroll
  for (int kh = 0; kh < 2; ++kh) {
    // write staged registers to LDS (cvt A inline)
    #pragma unroll
    for (int i = 0; i < 4; ++i) {
      int ci = tid + i * 256, r = ci >> 4, c8 = (ci & 15) * 8;
      float4 u0 = apre[i][0], u1 = apre[i][1];
      half8 h = {(_Float16)(u0.x * wscale), (_Float16)(u0.y * wscale),
                 (_Float16)(u0.z * wscale), (_Float16)(u0.w * wscale),
                 (_Float16)(u1.x * wscale), (_Float16)(u1.y * wscale),
                 (_Float16)(u1.z * wscale), (_Float16)(u1.w * wscale)};
      *(half8*)&As[r][c8] = h;
    }
    #pragma unroll
    for (int i = 0; i < 8; ++i) {
      int ci = tid + i * 256, r = ci >> 4, c8 = (ci & 15) * 8;
      *(half8*)&Bs[r][c8] = bpre[i];
    }
    if (kh == 0) {                            // prefetch kh=1 during MFMAs
      #pragma unroll
      for (int i = 0; i < 4; ++i) {
        int ci = tid + i * 256, r = ci >> 4, c8 = (ci & 15) * 8;
        const float* s = Ag + (size_t)r * CIN + 128 + c8;
        apre[i][0] = *(const float4*)s;
        apre[i][1] = *(const float4*)(s + 4);
      }
      #pragma unroll
      for (int i = 0; i < 8; ++i) {
        int ci = tid + i * 256, r = ci >> 4, c8 = (ci & 15) * 8;
        bpre[i] = *(const half8*)(Bg + (size_t)r * CIN + 128 + c8);
      }
    }
    __syncthreads();
    #pragma unroll
    for (int ks = 0; ks < 4; ++ks) {
      half8 a = *(const half8*)&As[wv * 16 + lm][ks * 32 + quad * 8];
      #pragma unroll
      for (int ns = 0; ns < 8; ++ns) {
        half8 bf = *(const half8*)&Bs[ns * 16 + lm][ks * 32 + quad * 8];
        acc[ns] = __builtin_amdgcn_mfma_f32_16x16x32_f16(a, bf, acc[ns], 0, 0, 0);
      }
    }
    if (kh == 0) __syncthreads();
  }

  // epilogue: m = wv*16 + quad*4 + r, n = ns*16 + lm
  const int sec = mt >> 1;                    // 0=Q 1=K 2=V
  const int o_base = (mt & 1) * 64 + wv * 16 + quad * 4;
  const int hh = o_base >> 5, dd = o_base & 31;
  const int bh = b * HEADS + hh;
  if (sec < 2) {
    _Float16* dst = (sec == 0) ? Qw : Kw;
    #pragma unroll
    for (int ns = 0; ns < 8; ++ns) {
      int p = p0 + ns * 16 + lm;
      half4 v = {(_Float16)acc[ns][0], (_Float16)acc[ns][1],
                 (_Float16)acc[ns][2], (_Float16)acc[ns][3]};
      *(half4*)(dst + ((size_t)bh * HW + p) * DH + dd) = v;
    }
  } else {
    #pragma unroll
    for (int ns = 0; ns < 8; ++ns) {
      int p = p0 + ns * 16 + lm;
      #pragma unroll
      for (int r = 0; r < 4; ++r)
        Vtw[((size_t)bh * DH + dd + r) * HW + p] = (_Float16)acc[ns][r];
    }
  }
}

// ---------------------------------------------------------------------------
// attn: round-9 register-dataflow flash attention (known 77.5 us), with one
// change: 1-D grid 512, bh = id & 15 so id % 8 == bh % 8 -> all 32 blocks of
// a bh land on one XCD (2 bh x 1 MB K/V per 4 MB L2) for L2 locality.
// 2 q-tiles per wave; 128-wide K-step; ping-pong; one barrier per step.
// ---------------------------------------------------------------------------
__global__ __launch_bounds__(256) void attn(
    const _Float16* __restrict__ Qw, const _Float16* __restrict__ Kw,
    const _Float16* __restrict__ Vtw, _Float16* __restrict__ Ot)
{
  __shared__ _Float16 ks[2][2][64][40];       // [phase][sub][kcol][d]
  __shared__ _Float16 vt[2][2][32][74];       // [phase][sub][d][kcol]

  const int bh = blockIdx.x & 15, qt = blockIdx.x >> 4;
  const int tid = threadIdx.x;
  const int wv = tid >> 6, lane = tid & 63, lm = lane & 15, quad = lane >> 4;

  const _Float16* qbase =
      Qw + ((size_t)bh * HW + qt * 128 + wv * 16 + lm) * DH + quad * 8;
  const half8 qa0 = *(const half8*)qbase;
  const half8 qa1 = *(const half8*)(qbase + (size_t)64 * DH);

  const _Float16 one = (_Float16)1.0f;
  const half4 ones4 = {one, one, one, one};
  const floatx4 shiftc = {-SHIFT2, -SHIFT2, -SHIFT2, -SHIFT2};

  floatx4 oT[2][2] = {{{0,0,0,0},{0,0,0,0}},{{0,0,0,0},{0,0,0,0}}};
  floatx4 l4[2]    = {{0,0,0,0},{0,0,0,0}};

  const _Float16* kbase = Kw  + (size_t)bh * HW * DH;
  const _Float16* vbase = Vtw + (size_t)bh * DH * HW;
  const int kr = tid >> 2, kc = (tid & 3) * 8;
  const int vr = tid >> 3, vc = (tid & 7) * 8;

  // prologue: stage subtiles 0,1; prefetch 2,3
  half8 kA = *(const half8*)(kbase + (size_t)kr * DH + kc);
  half8 vA = *(const half8*)(vbase + (size_t)vr * HW + vc);
  half8 kB = *(const half8*)(kbase + ((size_t)64 + kr) * DH + kc);
  half8 vB = *(const half8*)(vbase + (size_t)vr * HW + 64 + vc);
  *(half8*)&ks[0][0][kr][kc] = kA;
  *(half8*)&vt[0][0][vr][vc] = vA;
  *(half8*)&ks[0][1][kr][kc] = kB;
  *(half8*)&vt[0][1][vr][vc] = vB;
  kA = *(const half8*)(kbase + ((size_t)128 + kr) * DH + kc);
  vA = *(const half8*)(vbase + (size_t)vr * HW + 128 + vc);
  kB = *(const half8*)(kbase + ((size_t)192 + kr) * DH + kc);
  vB = *(const half8*)(vbase + (size_t)vr * HW + 192 + vc);
  __syncthreads();

  for (int it = 0; it < HW / 128; ++it) {
    const int ph = it & 1, nx = ph ^ 1;
    *(half8*)&ks[nx][0][kr][kc] = kA;
    *(half8*)&vt[nx][0][vr][vc] = vA;
    *(half8*)&ks[nx][1][kr][kc] = kB;
    *(half8*)&vt[nx][1][vr][vc] = vB;
    // prefetch subtiles (2it+4, 2it+5), clamped to stay in-bounds
    size_t koff = (size_t)(it * 2 + 4) * 64;
    if (koff > HW - 128) koff = HW - 128;
    kA = *(const half8*)(kbase + (koff + kr) * DH + kc);
    vA = *(const half8*)(vbase + (size_t)vr * HW + koff + vc);
    kB = *(const half8*)(kbase + (koff + 64 + kr) * DH + kc);
    vB = *(const half8*)(vbase + (size_t)vr * HW + koff + 64 + vc);

    #pragma unroll
    for (int sub = 0; sub < 2; ++sub) {
      #pragma unroll
      for (int f = 0; f < 4; ++f) {
        // S^T for both q-tiles off one kb read
        half8 kb = *(const half8*)&ks[ph][sub][f * 16 + lm][quad * 8];
        floatx4 sT0 = __builtin_amdgcn_mfma_f32_16x16x32_f16(kb, qa0, shiftc, 0, 0, 0);
        floatx4 sT1 = __builtin_amdgcn_mfma_f32_16x16x32_f16(kb, qa1, shiftc, 0, 0, 0);
        // P^T fragments in-register (packed cvt)
        half2v a0 = pk2(__builtin_amdgcn_exp2f(sT0[0]), __builtin_amdgcn_exp2f(sT0[1]));
        half2v b0 = pk2(__builtin_amdgcn_exp2f(sT0[2]), __builtin_amdgcn_exp2f(sT0[3]));
        half2v a1 = pk2(__builtin_amdgcn_exp2f(sT1[0]), __builtin_amdgcn_exp2f(sT1[1]));
        half2v b1 = pk2(__builtin_amdgcn_exp2f(sT1[2]), __builtin_amdgcn_exp2f(sT1[3]));
        half4 pb0 = {a0.x, a0.y, b0.x, b0.y};
        half4 pb1 = {a1.x, a1.y, b1.x, b1.y};
        l4[0] = __builtin_amdgcn_mfma_f32_16x16x16f16(ones4, pb0, l4[0], 0, 0, 0);
        l4[1] = __builtin_amdgcn_mfma_f32_16x16x16f16(ones4, pb1, l4[1], 0, 0, 0);
        #pragma unroll
        for (int g = 0; g < 2; ++g) {
          // one va read feeds both q-tiles' PV MFMAs
          half4 va = *(const half4*)&vt[ph][sub][g * 16 + lm][f * 16 + quad * 4];
          oT[0][g] = __builtin_amdgcn_mfma_f32_16x16x16f16(va, pb0, oT[0][g], 0, 0, 0);
          oT[1][g] = __builtin_amdgcn_mfma_f32_16x16x16f16(va, pb1, oT[1][g], 0, 0, 0);
        }
      }
    }
    __syncthreads();
  }

  // epilogue: lane-local normalize, coalesced half4 stores -> Ot[b][p][hid]
  const int b = bh >> 2, hh = bh & 3;
  #pragma unroll
  for (int t = 0; t < 2; ++t) {
    const float inv = 1.0f / l4[t][0];
    _Float16* obase = Ot +
        ((size_t)(b * HW + qt * 128 + t * 64 + wv * 16 + lm)) * HID + hh * DH;
    #pragma unroll
    for (int g = 0; g < 2; ++g) {
      half4 v = {(_Float16)(oT[t][g][0] * inv), (_Float16)(oT[t][g][1] * inv),
                 (_Float16)(oT[t][g][2] * inv), (_Float16)(oT[t][g][3] * inv)};
      *(half4*)(obase + g * 16 + quad * 4) = v;
    }
  }
}

// ---------------------------------------------------------------------------
// out_gemm: out[o][b,p] = w_out(256x128, cvt inline) @ Ot^T + bias.
// Tile 64x64, K=128. grid (4 m-tiles, 256 n-tiles) x 256.
// ---------------------------------------------------------------------------
__global__ __launch_bounds__(256) void out_gemm(
    const float* __restrict__ wo, const _Float16* __restrict__ Ot,
    const float* __restrict__ bo, float* __restrict__ out)
{
  __shared__ _Float16 As[64][136];
  __shared__ _Float16 Bs[64][136];
  __shared__ float os[64][68];
  const int mt = blockIdx.x, nt = blockIdx.y;
  const int b = nt >> 6, p0 = (nt & 63) * 64;
  const int tid = threadIdx.x;
  const int wv = tid >> 6, lane = tid & 63, lm = lane & 15, quad = lane >> 4;

  const float* Ag = wo + (size_t)(mt * 64) * HID;
  const _Float16* B = Ot + ((size_t)b * HW + p0) * HID;

  #pragma unroll
  for (int i = 0; i < 4; ++i) {
    int ci = tid + i * 256;
    int r = ci >> 4, c8 = (ci & 15) * 8;
    const float* src = Ag + (size_t)r * HID + c8;
    float4 u0 = *(const float4*)(src);
    float4 u1 = *(const float4*)(src + 4);
    half8 h = {(_Float16)u0.x, (_Float16)u0.y, (_Float16)u0.z, (_Float16)u0.w,
               (_Float16)u1.x, (_Float16)u1.y, (_Float16)u1.z, (_Float16)u1.w};
    *(half8*)&As[r][c8] = h;
    *(half8*)&Bs[r][c8] = *(const half8*)(B + (size_t)r * HID + c8);
  }
  __syncthreads();

  floatx4 acc[4] = {{0,0,0,0},{0,0,0,0},{0,0,0,0},{0,0,0,0}};
  #pragma unroll
  for (int ks = 0; ks < 4; ++ks) {
    half8 a = *(const half8*)&As[wv * 16 + lm][ks * 32 + quad * 8];
    #pragma unroll
    for (int ns = 0; ns < 4; ++ns) {
      half8 bf = *(const half8*)&Bs[ns * 16 + lm][ks * 32 + quad * 8];
      acc[ns] = __builtin_amdgcn_mfma_f32_16x16x32_f16(a, bf, acc[ns], 0, 0, 0);
    }
  }

  #pragma unroll
  for (int ns = 0; ns < 4; ++ns)
    #pragma unroll
    for (int r = 0; r < 4; ++r)
      os[wv * 16 + quad * 4 + r][ns * 16 + lm] = acc[ns][r];
  __syncthreads();

  const int o = tid >> 2, pq = (tid & 3) * 16;
  const float bias = bo[mt * 64 + o];
  float* dst = out + ((size_t)(b * CIN + mt * 64 + o)) * HW + p0 + pq;
  #pragma unroll
  for (int j = 0; j < 4; ++j) {
    float4 v = *(const float4*)&os[o][pq + j * 4];
    v.x += bias; v.y += bias; v.z += bias; v.w += bias;
    *(float4*)(dst + j * 4) = v;
  }
}

// ---------------------------------------------------------------------------
extern "C" void kernel_launch(void* const* d_in, const int* in_sizes, int n_in,
                              void* d_out, int out_size, void* d_ws, size_t ws_size,
                              hipStream_t stream)
{
  const float* x     = (const float*)d_in[0];   // [4,256,64,64]
  const float* w_qkv = (const float*)d_in[1];   // [384,256]
  const float* w_out = (const float*)d_in[2];   // [256,128]
  const float* b_out = (const float*)d_in[3];   // [256]
  float* out = (float*)d_out;

  char* ws = (char*)d_ws;
  _Float16* Xh  = (_Float16*)(ws);               // 8 MB [4][4096][256]
  _Float16* Ot  = (_Float16*)(ws);               // 4 MB (reuses Xh after qkv)
  _Float16* Qw  = (_Float16*)(ws + (8u  << 20)); // 4 MB [bh][p][d], log2e-scaled
  _Float16* Kw  = (_Float16*)(ws + (12u << 20)); // 4 MB [bh][p][d]
  _Float16* Vtw = (_Float16*)(ws + (16u << 20)); // 4 MB [bh][d][p]

  dim3 blk(256);
  conv_x<<<dim3(64, 4, 4), blk, 0, stream>>>(x, Xh);
  qkv_gemm<<<dim3(6, 128), blk, 0, stream>>>(w_qkv, Xh, Qw, Kw, Vtw);
  attn<<<dim3(512), blk, 0, stream>>>(Qw, Kw, Vtw, Ot);
  out_gemm<<<dim3(4, 256), blk, 0, stream>>>(w_out, Ot, b_out, out);
}